// Round 4
// baseline (420.390 us; speedup 1.0000x reference)
//
#include <hip/hip_runtime.h>
#include <math.h>

// Workspace float offsets
#define OFF_A      0u          // A (16,2048,256) fp32          8388608
#define OFF_P      8388608u    // cc1 partials [8][16][256][64] 2097152
#define OFF_WCC1   10485760u   // [c2][oc][4]                    524288
#define OFF_BCC1   11010048u   // 64
#define OFF_WCC2   11010112u   // [ic][oc][4]                     16384
#define OFF_BCC2   11026496u   // 64
#define OFF_WRD1   11026560u   // [ic64][oc128][4]                32768
#define OFF_BRD1   11059328u   // 128
#define OFF_WRD2   11059456u   // [ic128][oc128][4]               65536
#define OFF_BRD2   11124992u   // 128
#define OFF_WUP1   11125120u   // [v3][ic128][oc64][4]            98304
#define OFF_BUP1   11223424u   // 64
#define OFF_WUP2   11223488u   // [v5][src3][ic64][oc32][4]      122880
#define OFF_BUP2   11346368u   // 32
#define OFF_WRX    11346400u   // folded rx weights [rxi][ic32][oc32] 4096
// Aliased over A (A dead after k_cc1):
#define OFF_R      0u          // R [16][256][128]               524288
#define OFF_U1     524288u     // U1 [16][3][256][64]            786432
#define OFF_H      1310720u    // H [16][5][256]                  20480
// total ws floats 11350496 (~43.3 MiB)

__device__ __forceinline__ void fma4(float4& a, const float4& x, float w) {
  a.x = fmaf(x.x, w, a.x); a.y = fmaf(x.y, w, a.y);
  a.z = fmaf(x.z, w, a.z); a.w = fmaf(x.w, w, a.w);
}

// ---------------------------------------------------------------- repack ----
__global__ __launch_bounds__(256) void k_repack(
    const float* __restrict__ rx_w, const float* __restrict__ rx_s,
    const float* __restrict__ cc1_w, const float* __restrict__ cc1_b, const float* __restrict__ cc1_s, const float* __restrict__ cc1_t,
    const float* __restrict__ cc2_w, const float* __restrict__ cc2_b, const float* __restrict__ cc2_s, const float* __restrict__ cc2_t,
    const float* __restrict__ rd1_w, const float* __restrict__ rd1_b, const float* __restrict__ rd1_s, const float* __restrict__ rd1_t,
    const float* __restrict__ rd2_w, const float* __restrict__ rd2_b, const float* __restrict__ rd2_s, const float* __restrict__ rd2_t,
    const float* __restrict__ up1_w, const float* __restrict__ up1_b, const float* __restrict__ up1_s, const float* __restrict__ up1_t,
    const float* __restrict__ up2_w, const float* __restrict__ up2_b, const float* __restrict__ up2_s, const float* __restrict__ up2_t,
    float* __restrict__ ws)
{
  const int tid = blockIdx.x * blockDim.x + threadIdx.x;
  const int nth = gridDim.x * blockDim.x;

  // folded rx weights: [rxi][ic][oc]
  for (int i = tid; i < 4096; i += nth) {
    int oc = i & 31, ic = (i >> 5) & 31, rxi = i >> 10;
    ws[OFF_WRX + i] = rx_w[(oc*32 + ic)*4 + rxi] * rx_s[oc];
  }

  for (int i = tid; i < 2048*64*4; i += nth) {
    int k = i & 3, oc = (i >> 2) & 63, c2 = i >> 8;
    ws[OFF_WCC1 + i] = (k < 3) ? cc1_w[((oc*2048 + c2)*3 + 1)*3 + k] * cc1_s[oc] : 0.f;
  }
  for (int i = tid; i < 64; i += nth) ws[OFF_BCC1 + i] = cc1_b[i]*cc1_s[i] + cc1_t[i];

  for (int i = tid; i < 64*64*4; i += nth) {
    int k = i & 3, oc = (i >> 2) & 63, ic = i >> 8;
    ws[OFF_WCC2 + i] = (k < 3) ? cc2_w[((oc*64 + ic)*3 + 1)*3 + k] * cc2_s[oc] : 0.f;
  }
  for (int i = tid; i < 64; i += nth) ws[OFF_BCC2 + i] = cc2_b[i]*cc2_s[i] + cc2_t[i];

  for (int i = tid; i < 64*128*4; i += nth) {
    int k = i & 3, oc = (i >> 2) & 127, ic = i >> 9;
    ws[OFF_WRD1 + i] = (k < 3) ? rd1_w[((oc*64 + ic)*3 + 1)*3 + k] * rd1_s[oc] : 0.f;
  }
  for (int i = tid; i < 128; i += nth) ws[OFF_BRD1 + i] = rd1_b[i]*rd1_s[i] + rd1_t[i];

  for (int i = tid; i < 128*128*4; i += nth) {
    int k = i & 3, oc = (i >> 2) & 127, ic = i >> 9;
    ws[OFF_WRD2 + i] = (k < 3) ? rd2_w[((oc*128 + ic)*3 + 1)*3 + k] * rd2_s[oc] : 0.f;
  }
  for (int i = tid; i < 128; i += nth) ws[OFF_BRD2 + i] = rd2_b[i]*rd2_s[i] + rd2_t[i];

  for (int i = tid; i < 3*128*64*4; i += nth) {
    int k = i & 3, oc = (i >> 2) & 63, ic = (i >> 8) & 127, v = i >> 15;
    float val = 0.f;
    if (k < 3) {
      const int m = (v == 0) ? 6 : (v == 1) ? 7 : 3;
      float a = 0.f;
      for (int kh = 0; kh < 3; ++kh)
        if ((m >> kh) & 1) a += up1_w[((oc*128 + ic)*3 + kh)*3 + k];
      val = a * up1_s[oc];
    }
    ws[OFF_WUP1 + i] = val;
  }
  for (int i = tid; i < 64; i += nth) ws[OFF_BUP1 + i] = up1_b[i]*up1_s[i] + up1_t[i];

  for (int i = tid; i < 5*3*64*32*4; i += nth) {
    int k = i & 3, oc = (i >> 2) & 31, ic = (i >> 7) & 63, t = i >> 13;
    int src = t % 3, v = t / 3;
    float val = 0.f;
    if (k < 3) {
      const int MASKS[15] = {2,4,0,  1,6,0,  0,7,0,  0,3,4,  0,1,2};
      const int m = MASKS[v*3 + src];
      float a = 0.f;
      for (int kh = 0; kh < 3; ++kh)
        if ((m >> kh) & 1) a += up2_w[((oc*64 + ic)*3 + kh)*3 + k];
      val = a * up2_s[oc];
    }
    ws[OFF_WUP2 + i] = val;
  }
  for (int i = tid; i < 32; i += nth) ws[OFF_BUP2 + i] = up2_b[i]*up2_s[i] + up2_t[i];
}

// ------------------------------------------------- fused tc1+tc2+rx ---------
// Block = (b, chirp). LDS ~39 KB -> 4 blocks/CU (16 waves) for latency hiding.
// t2 computed/consumed in two 16-channel halves; rx weights read from global
// (pre-folded, wave-uniform addresses -> broadcast L1 hits).
__global__ __launch_bounds__(256) void k_front(
    const float* __restrict__ x,
    const float* __restrict__ w1, const float* __restrict__ b1, const float* __restrict__ s1, const float* __restrict__ t1bn,
    const float* __restrict__ w2, const float* __restrict__ b2, const float* __restrict__ s2, const float* __restrict__ t2bn,
    const float* __restrict__ wrxF, const float* __restrict__ brx, const float* __restrict__ srx, const float* __restrict__ trx,
    float* __restrict__ A)
{
  __shared__ __align__(16) float t1s[16][256];     // 16 KB
  __shared__ __align__(16) float t2s[16][256];     // 16 KB (one half of t2)
  __shared__ __align__(16) float w1f[16][6];
  __shared__ float b1f[16];
  __shared__ __align__(16) float w2t[16][3][32];   // [ic][k][oc]  6 KB
  __shared__ float b2f[32];
  __shared__ float brxf[32];

  const int tid = threadIdx.x;
  const int b = blockIdx.x >> 6, chirp = blockIdx.x & 63;

  if (tid < 96) (&w1f[0][0])[tid] = w1[tid] * s1[tid/6];
  if (tid < 16) b1f[tid] = b1[tid]*s1[tid] + t1bn[tid];
  for (int i = tid; i < 1536; i += 256) {
    int oc = i / 48, r = i - oc*48, ic = r / 3, k = r - ic*3;
    w2t[ic][k][oc] = w2[i] * s2[oc];
  }
  if (tid < 32) b2f[tid] = b2[tid]*s2[tid] + t2bn[tid];
  if (tid < 32) brxf[tid] = brx[tid]*srx[tid] + trx[tid];
  __syncthreads();

  const int s  = tid;           // phase A sample
  const int sg = tid & 63;      // sample group (contiguous lanes)
  const int q  = tid >> 6;      // wave index (uniform within wave)
  const int s0 = sg * 4;

  float4 acc[8];                // 8 oc (q*8..q*8+8) x 4 samples
  #pragma unroll
  for (int j = 0; j < 8; ++j) acc[j] = make_float4(0.f, 0.f, 0.f, 0.f);

  #pragma unroll 1
  for (int rxi = 0; rxi < 4; ++rxi) {
    // ---- phase A: t1 for my sample ----
    {
      const float2* xb2 = (const float2*)(x + ((size_t)(((b*4 + rxi)*64 + chirp)*256) << 1));
      float2 xm = xb2[s];
      float2 xl = xb2[(s == 0) ? 0 : (s - 1)];
      float2 xr = xb2[(s == 255) ? 255 : (s + 1)];
      if (s == 0)   { xl.x = 0.f; xl.y = 0.f; }
      if (s == 255) { xr.x = 0.f; xr.y = 0.f; }
      #pragma unroll 4
      for (int o = 0; o < 16; ++o) {
        float v = b1f[o];
        v = fmaf(xl.x, w1f[o][0], v);
        v = fmaf(xm.x, w1f[o][1], v);
        v = fmaf(xr.x, w1f[o][2], v);
        v = fmaf(xl.y, w1f[o][3], v);
        v = fmaf(xm.y, w1f[o][4], v);
        v = fmaf(xr.y, w1f[o][5], v);
        t1s[o][s] = fmaxf(v, 0.f);
      }
    }
    __syncthreads();

    #pragma unroll 1
    for (int h = 0; h < 2; ++h) {
      // ---- phase B: t2 channels [h*16, h*16+16), thread = 4 samples x 4 oc
      {
        const int ocb = h*16 + q*4;     // wave-uniform
        float4 t2a[4];
        #pragma unroll
        for (int j = 0; j < 4; ++j) {
          float bv = b2f[ocb + j];
          t2a[j] = make_float4(bv, bv, bv, bv);
        }
        #pragma unroll 4
        for (int ic = 0; ic < 16; ++ic) {
          float4 tm = *(const float4*)&t1s[ic][s0];
          float tl = t1s[ic][(sg == 0) ? 0 : (s0 - 1)];
          float tr = t1s[ic][(sg == 63) ? 255 : (s0 + 4)];
          if (sg == 0)  tl = 0.f;
          if (sg == 63) tr = 0.f;
          float4 win0 = make_float4(tl, tm.x, tm.y, tm.z);
          float4 win2 = make_float4(tm.y, tm.z, tm.w, tr);
          float4 wA = *(const float4*)&w2t[ic][0][ocb];
          float4 wB = *(const float4*)&w2t[ic][1][ocb];
          float4 wC = *(const float4*)&w2t[ic][2][ocb];
          fma4(t2a[0], win0, wA.x); fma4(t2a[0], tm, wB.x); fma4(t2a[0], win2, wC.x);
          fma4(t2a[1], win0, wA.y); fma4(t2a[1], tm, wB.y); fma4(t2a[1], win2, wC.y);
          fma4(t2a[2], win0, wA.z); fma4(t2a[2], tm, wB.z); fma4(t2a[2], win2, wC.z);
          fma4(t2a[3], win0, wA.w); fma4(t2a[3], tm, wB.w); fma4(t2a[3], win2, wC.w);
        }
        #pragma unroll
        for (int j = 0; j < 4; ++j) {
          float4 r;
          r.x = fmaxf(t2a[j].x, 0.f); r.y = fmaxf(t2a[j].y, 0.f);
          r.z = fmaxf(t2a[j].z, 0.f); r.w = fmaxf(t2a[j].w, 0.f);
          *(float4*)&t2s[q*4 + j][s0] = r;
        }
      }
      __syncthreads();

      // ---- phase C: rx 1x1 accumulate over these 16 channels ----
      {
        const float* wbase = wrxF + ((rxi*32 + h*16)*32) + q*8;  // wave-uniform
        #pragma unroll 8
        for (int ic = 0; ic < 16; ++ic) {
          float4 tv = *(const float4*)&t2s[ic][s0];
          float4 wa = *(const float4*)(wbase + ic*32);
          float4 wb = *(const float4*)(wbase + ic*32 + 4);
          fma4(acc[0], tv, wa.x); fma4(acc[1], tv, wa.y);
          fma4(acc[2], tv, wa.z); fma4(acc[3], tv, wa.w);
          fma4(acc[4], tv, wb.x); fma4(acc[5], tv, wb.y);
          fma4(acc[6], tv, wb.z); fma4(acc[7], tv, wb.w);
        }
      }
      __syncthreads();
    }
  }

  #pragma unroll
  for (int j = 0; j < 8; ++j) {
    int oc = q*8 + j;
    float bb = brxf[oc];
    float4 r;
    r.x = fmaxf(acc[j].x + bb, 0.f); r.y = fmaxf(acc[j].y + bb, 0.f);
    r.z = fmaxf(acc[j].z + bb, 0.f); r.w = fmaxf(acc[j].w + bb, 0.f);
    *(float4*)&A[(size_t)((b*2048 + oc*64 + chirp)*256) + s0] = r;
  }
}

// --------------------------------------------------------- cc1 (split-K8) ---
__global__ __launch_bounds__(256) void k_cc1(
    const float* __restrict__ A, const float* __restrict__ wp, float* __restrict__ P)
{
  __shared__ __align__(16) float As[256][36];   // samples s0-1 .. s0+32 at si 0..33
  const int tid = threadIdx.x;
  const int ks = blockIdx.x & 7;
  const int stile = (blockIdx.x >> 3) & 7;
  const int b = blockIdx.x >> 6;
  const int s0 = stile * 32;
  const int oc = tid & 63;
  const int sg = tid >> 6;
  const int cbase = ks * 256;
  const float4* w4 = (const float4*)wp;

  for (int i = tid; i < 256*36; i += 256) {
    int c = i / 36, si = i - c*36;
    int sA = s0 - 1 + si;
    float v = 0.f;
    if (si < 34 && sA >= 0 && sA < 256)
      v = A[(size_t)(b*2048 + cbase + c)*256 + sA];
    As[c][si] = v;
  }
  __syncthreads();

  const int sb = sg * 8;
  float4 acc0 = make_float4(0.f,0.f,0.f,0.f);
  float4 acc1 = make_float4(0.f,0.f,0.f,0.f);
  #pragma unroll 4
  for (int c = 0; c < 256; ++c) {
    float4 w = w4[(size_t)(cbase + c)*64 + oc];
    float4 a0 = *(const float4*)&As[c][sb];
    float4 a1 = *(const float4*)&As[c][sb + 4];
    float2 a2 = *(const float2*)&As[c][sb + 8];
    acc0.x = fmaf(a0.x,w.x, fmaf(a0.y,w.y, fmaf(a0.z,w.z, acc0.x)));
    acc0.y = fmaf(a0.y,w.x, fmaf(a0.z,w.y, fmaf(a0.w,w.z, acc0.y)));
    acc0.z = fmaf(a0.z,w.x, fmaf(a0.w,w.y, fmaf(a1.x,w.z, acc0.z)));
    acc0.w = fmaf(a0.w,w.x, fmaf(a1.x,w.y, fmaf(a1.y,w.z, acc0.w)));
    acc1.x = fmaf(a1.x,w.x, fmaf(a1.y,w.y, fmaf(a1.z,w.z, acc1.x)));
    acc1.y = fmaf(a1.y,w.x, fmaf(a1.z,w.y, fmaf(a1.w,w.z, acc1.y)));
    acc1.z = fmaf(a1.z,w.x, fmaf(a1.w,w.y, fmaf(a2.x,w.z, acc1.z)));
    acc1.w = fmaf(a1.w,w.x, fmaf(a2.x,w.y, fmaf(a2.y,w.z, acc1.w)));
  }
  float* Pk = P + ((size_t)(ks*16 + b)*256)*64;
  int s = s0 + sb;
  Pk[(size_t)(s+0)*64 + oc] = acc0.x;
  Pk[(size_t)(s+1)*64 + oc] = acc0.y;
  Pk[(size_t)(s+2)*64 + oc] = acc0.z;
  Pk[(size_t)(s+3)*64 + oc] = acc0.w;
  Pk[(size_t)(s+4)*64 + oc] = acc1.x;
  Pk[(size_t)(s+5)*64 + oc] = acc1.y;
  Pk[(size_t)(s+6)*64 + oc] = acc1.z;
  Pk[(size_t)(s+7)*64 + oc] = acc1.w;
}

// ------------------------------------------- fused cc2 + rd1 + rd2 ----------
__global__ __launch_bounds__(256) void k_mid(
    const float* __restrict__ P, const float* __restrict__ bcc1,
    const float* __restrict__ wcc2, const float* __restrict__ bcc2,
    const float* __restrict__ wrd1, const float* __restrict__ brd1,
    const float* __restrict__ wrd2, const float* __restrict__ brd2,
    float* __restrict__ R)
{
  __shared__ float c1s[14][64];   // c1 at s0-3 .. s0+10
  __shared__ float c2s[14][64];   // c2 at s0-2 .. s0+9 (rows 12,13 zero pad)
  __shared__ float r1s[10][128];  // r1 at s0-1 .. s0+8
  const int tid = threadIdx.x;
  const int b = blockIdx.x >> 5;
  const int s0 = (blockIdx.x & 31) * 8;
  const float4* wc2 = (const float4*)wcc2;
  const float4* wr1 = (const float4*)wrd1;
  const float4* wr2 = (const float4*)wrd2;

  for (int i = tid; i < 14*64; i += 256) {
    int si = i >> 6, ic = i & 63;
    int sA = s0 - 3 + si;
    float v = 0.f;
    if (sA >= 0 && sA < 256) {
      float a = bcc1[ic];
      #pragma unroll
      for (int ksp = 0; ksp < 8; ++ksp)
        a += P[((size_t)(ksp*16 + b)*256 + sA)*64 + ic];
      v = fmaxf(a, 0.f);
    }
    c1s[si][ic] = v;
  }
  __syncthreads();

  {
    const int g = tid >> 6, oc = tid & 63;
    if (g < 3) {
      float4 acc;
      float bb = bcc2[oc];
      acc = make_float4(bb, bb, bb, bb);
      for (int ic = 0; ic < 64; ++ic) {
        float4 w = wc2[ic*64 + oc];
        float c0 = c1s[g*4+0][ic], c1 = c1s[g*4+1][ic], c2 = c1s[g*4+2][ic];
        float c3 = c1s[g*4+3][ic], c4 = c1s[g*4+4][ic], c5 = c1s[g*4+5][ic];
        acc.x = fmaf(c0,w.x, fmaf(c1,w.y, fmaf(c2,w.z, acc.x)));
        acc.y = fmaf(c1,w.x, fmaf(c2,w.y, fmaf(c3,w.z, acc.y)));
        acc.z = fmaf(c2,w.x, fmaf(c3,w.y, fmaf(c4,w.z, acc.z)));
        acc.w = fmaf(c3,w.x, fmaf(c4,w.y, fmaf(c5,w.z, acc.w)));
      }
      c2s[g*4+0][oc] = fmaxf(acc.x, 0.f);
      c2s[g*4+1][oc] = fmaxf(acc.y, 0.f);
      c2s[g*4+2][oc] = fmaxf(acc.z, 0.f);
      c2s[g*4+3][oc] = fmaxf(acc.w, 0.f);
    } else {
      int k = tid - 192;
      c2s[12][k] = 0.f;
      c2s[13][k] = 0.f;
    }
  }
  __syncthreads();

  for (int it = tid; it < 384; it += 256) {
    const int oc = it & 127, g = it >> 7;
    float4 acc;
    float bb = brd1[oc];
    acc = make_float4(bb, bb, bb, bb);
    for (int ic = 0; ic < 64; ++ic) {
      float4 w = wr1[ic*128 + oc];
      float c0 = c2s[g*4+0][ic], c1 = c2s[g*4+1][ic], c2 = c2s[g*4+2][ic];
      float c3 = c2s[g*4+3][ic], c4 = c2s[g*4+4][ic], c5 = c2s[g*4+5][ic];
      acc.x = fmaf(c0,w.x, fmaf(c1,w.y, fmaf(c2,w.z, acc.x)));
      acc.y = fmaf(c1,w.x, fmaf(c2,w.y, fmaf(c3,w.z, acc.y)));
      acc.z = fmaf(c2,w.x, fmaf(c3,w.y, fmaf(c4,w.z, acc.z)));
      acc.w = fmaf(c3,w.x, fmaf(c4,w.y, fmaf(c5,w.z, acc.w)));
    }
    r1s[g*4+0][oc] = fmaxf(acc.x, 0.f);
    r1s[g*4+1][oc] = fmaxf(acc.y, 0.f);
    if (g < 2) {
      r1s[g*4+2][oc] = fmaxf(acc.z, 0.f);
      r1s[g*4+3][oc] = fmaxf(acc.w, 0.f);
    }
  }
  __syncthreads();

  {
    const int g = tid >> 7, oc = tid & 127;
    float4 acc;
    float bb = brd2[oc];
    acc = make_float4(bb, bb, bb, bb);
    for (int ic = 0; ic < 128; ++ic) {
      float4 w = wr2[ic*128 + oc];
      float c0 = r1s[g*4+0][ic], c1 = r1s[g*4+1][ic], c2 = r1s[g*4+2][ic];
      float c3 = r1s[g*4+3][ic], c4 = r1s[g*4+4][ic], c5 = r1s[g*4+5][ic];
      acc.x = fmaf(c0,w.x, fmaf(c1,w.y, fmaf(c2,w.z, acc.x)));
      acc.y = fmaf(c1,w.x, fmaf(c2,w.y, fmaf(c3,w.z, acc.y)));
      acc.z = fmaf(c2,w.x, fmaf(c3,w.y, fmaf(c4,w.z, acc.z)));
      acc.w = fmaf(c3,w.x, fmaf(c4,w.y, fmaf(c5,w.z, acc.w)));
    }
    int s = s0 + g*4;
    R[((size_t)b*256 + s+0)*128 + oc] = fmaxf(acc.x, 0.f);
    R[((size_t)b*256 + s+1)*128 + oc] = fmaxf(acc.y, 0.f);
    R[((size_t)b*256 + s+2)*128 + oc] = fmaxf(acc.z, 0.f);
    R[((size_t)b*256 + s+3)*128 + oc] = fmaxf(acc.w, 0.f);
  }
}

// --------------------------------------- up1 on 3 distinct rows -------------
__global__ __launch_bounds__(192) void k_up1(
    const float* __restrict__ R, const float* __restrict__ wup1, const float* __restrict__ bup1,
    float* __restrict__ U1)
{
  __shared__ float Rs[10][128];   // s0-1 .. s0+8
  const int tid = threadIdx.x;
  const int b = blockIdx.x >> 5;
  const int s0 = (blockIdx.x & 31) * 8;
  for (int i = tid; i < 10*128; i += 192) {
    int si = i >> 7, ic = i & 127;
    int sA = s0 - 1 + si;
    Rs[si][ic] = (sA >= 0 && sA < 256) ? R[((size_t)b*256 + sA)*128 + ic] : 0.f;
  }
  __syncthreads();
  const int vi = tid >> 6, oc = tid & 63;
  const float4* w4 = (const float4*)wup1;
  float acc[8];
  float bb = bup1[oc];
  #pragma unroll
  for (int j = 0; j < 8; ++j) acc[j] = bb;
  for (int ic = 0; ic < 128; ++ic) {
    float4 w = w4[(vi*128 + ic)*64 + oc];
    float r0 = Rs[0][ic], r1 = Rs[1][ic], r2 = Rs[2][ic], r3 = Rs[3][ic], r4 = Rs[4][ic];
    float r5 = Rs[5][ic], r6 = Rs[6][ic], r7 = Rs[7][ic], r8 = Rs[8][ic], r9 = Rs[9][ic];
    acc[0] = fmaf(r0,w.x, fmaf(r1,w.y, fmaf(r2,w.z, acc[0])));
    acc[1] = fmaf(r1,w.x, fmaf(r2,w.y, fmaf(r3,w.z, acc[1])));
    acc[2] = fmaf(r2,w.x, fmaf(r3,w.y, fmaf(r4,w.z, acc[2])));
    acc[3] = fmaf(r3,w.x, fmaf(r4,w.y, fmaf(r5,w.z, acc[3])));
    acc[4] = fmaf(r4,w.x, fmaf(r5,w.y, fmaf(r6,w.z, acc[4])));
    acc[5] = fmaf(r5,w.x, fmaf(r6,w.y, fmaf(r7,w.z, acc[5])));
    acc[6] = fmaf(r6,w.x, fmaf(r7,w.y, fmaf(r8,w.z, acc[6])));
    acc[7] = fmaf(r7,w.x, fmaf(r8,w.y, fmaf(r9,w.z, acc[7])));
  }
  #pragma unroll
  for (int j = 0; j < 8; ++j)
    U1[((size_t)(b*3 + vi)*256 + s0 + j)*64 + oc] = fmaxf(acc[j], 0.f);
}

// ------------------------------- up2 (5 rows) + up3 + sigmoid ---------------
__global__ __launch_bounds__(192) void k_up2(
    const float* __restrict__ U1, const float* __restrict__ wup2, const float* __restrict__ bup2,
    const float* __restrict__ up3_w, const float* __restrict__ up3_b,
    float* __restrict__ H)
{
  __shared__ float u1s[3][10][64];
  __shared__ float u2s[5][32][9];
  const int tid = threadIdx.x;
  const int b = blockIdx.x >> 5;
  const int s0 = (blockIdx.x & 31) * 8;
  for (int i = tid; i < 3*10*64; i += 192) {
    int v = i / 640, r = i - v*640, si = r >> 6, ic = r & 63;
    int sA = s0 - 1 + si;
    u1s[v][si][ic] = (sA >= 0 && sA < 256) ? U1[((size_t)(b*3 + v)*256 + sA)*64 + ic] : 0.f;
  }
  __syncthreads();
  if (tid < 160) {
    const int v = tid >> 5, oc = tid & 31;
    const float4* w4 = (const float4*)wup2;
    float acc[8];
    float bb = bup2[oc];
    #pragma unroll
    for (int j = 0; j < 8; ++j) acc[j] = bb;
    for (int src = 0; src < 3; ++src)
      for (int ic = 0; ic < 64; ++ic) {
        float4 w = w4[((v*3 + src)*64 + ic)*32 + oc];
        float r0 = u1s[src][0][ic], r1 = u1s[src][1][ic], r2 = u1s[src][2][ic];
        float r3 = u1s[src][3][ic], r4 = u1s[src][4][ic], r5 = u1s[src][5][ic];
        float r6 = u1s[src][6][ic], r7 = u1s[src][7][ic], r8 = u1s[src][8][ic];
        float r9 = u1s[src][9][ic];
        acc[0] = fmaf(r0,w.x, fmaf(r1,w.y, fmaf(r2,w.z, acc[0])));
        acc[1] = fmaf(r1,w.x, fmaf(r2,w.y, fmaf(r3,w.z, acc[1])));
        acc[2] = fmaf(r2,w.x, fmaf(r3,w.y, fmaf(r4,w.z, acc[2])));
        acc[3] = fmaf(r3,w.x, fmaf(r4,w.y, fmaf(r5,w.z, acc[3])));
        acc[4] = fmaf(r4,w.x, fmaf(r5,w.y, fmaf(r6,w.z, acc[4])));
        acc[5] = fmaf(r5,w.x, fmaf(r6,w.y, fmaf(r7,w.z, acc[5])));
        acc[6] = fmaf(r6,w.x, fmaf(r7,w.y, fmaf(r8,w.z, acc[6])));
        acc[7] = fmaf(r7,w.x, fmaf(r8,w.y, fmaf(r9,w.z, acc[7])));
      }
    #pragma unroll
    for (int j = 0; j < 8; ++j) u2s[v][oc][j] = fmaxf(acc[j], 0.f);
  }
  __syncthreads();
  if (tid < 40) {
    int v = tid >> 3, j = tid & 7;
    float a = up3_b[0];
    for (int ic = 0; ic < 32; ++ic)
      a = fmaf(u2s[v][ic][j], up3_w[ic], a);
    H[(size_t)(b*5 + v)*256 + s0 + j] = 1.f / (1.f + expf(-a));
  }
}

// --------------------- range/Doppler spectral + magnitude + final -----------
__global__ __launch_bounds__(64) void k_spec(
    const float* __restrict__ H, const float* __restrict__ wr, const float* __restrict__ wd,
    float* __restrict__ out)
{
  __shared__ float hs[5][256];
  __shared__ float S0[64], S1[64];
  __shared__ float wds[4][64][2];
  const int tid = threadIdx.x;
  const int b = blockIdx.x >> 2;
  const int rt = blockIdx.x & 3;
  for (int i = tid; i < 1280; i += 64) hs[i >> 8][i & 255] = H[(size_t)b*1280 + i];
  {
    float a0 = 0.f, a1 = 0.f;
    for (int c = 2; c <= 61; ++c) {
      a0 += wd[(c*64 + tid)*2 + 0];
      a1 += wd[(c*64 + tid)*2 + 1];
    }
    S0[tid] = a0; S1[tid] = a1;
  }
  for (int i = tid; i < 512; i += 64) {
    int row = i >> 7, rem = i & 127, d = rem >> 1, comp = rem & 1;
    int c = (row < 2) ? row : (60 + row);   // rows 0,1,62,63
    wds[row][d][comp] = wd[(c*64 + d)*2 + comp];
  }
  __syncthreads();
  const int r = rt*64 + tid;
  float rr0=0,rr1=0,rr2=0,rr3=0,rr4=0, ri0=0,ri1=0,ri2=0,ri3=0,ri4=0;
  const float2* wr2p = (const float2*)wr;
  for (int s = 0; s < 256; ++s) {
    float2 w = wr2p[s*256 + r];
    float h0 = hs[0][s], h1 = hs[1][s], h2 = hs[2][s], h3 = hs[3][s], h4 = hs[4][s];
    rr0 = fmaf(h0, w.x, rr0); ri0 = fmaf(h0, w.y, ri0);
    rr1 = fmaf(h1, w.x, rr1); ri1 = fmaf(h1, w.y, ri1);
    rr2 = fmaf(h2, w.x, rr2); ri2 = fmaf(h2, w.y, ri2);
    rr3 = fmaf(h3, w.x, rr3); ri3 = fmaf(h3, w.y, ri3);
    rr4 = fmaf(h4, w.x, rr4); ri4 = fmaf(h4, w.y, ri4);
  }
  for (int d = 0; d < 64; ++d) {
    float w0r = wds[0][d][0], w0i = wds[0][d][1];
    float w1r = wds[1][d][0], w1i = wds[1][d][1];
    float w2r = wds[2][d][0], w2i = wds[2][d][1];
    float w3r = wds[3][d][0], w3i = wds[3][d][1];
    float s0v = S0[d], s1v = S1[d];
    float rdr = rr0*w0r + rr1*w1r + rr2*s0v + rr3*w2r + rr4*w3r
              - ri0*w0i - ri1*w1i - ri2*s1v - ri3*w2i - ri4*w3i;
    float rdi = rr0*w0i + rr1*w1i + rr2*s1v + rr3*w2i + rr4*w3i
              + ri0*w0r + ri1*w1r + ri2*s0v + ri3*w2r + ri4*w3r;
    float mag = sqrtf(rdr*rdr + rdi*rdi) * (1.0f / 16384.0f);
    int v = (d == 0) ? 0 : (d == 1) ? 1 : (d <= 61) ? 2 : ((d == 62) ? 3 : 4);
    float o = hs[v][r] + 0.1f * mag;
    out[(size_t)b*16384 + d*256 + r] = fminf(fmaxf(o, 0.f), 1.f);
  }
}

extern "C" void kernel_launch(void* const* d_in, const int* in_sizes, int n_in,
                              void* d_out, int out_size, void* d_ws, size_t ws_size,
                              hipStream_t stream)
{
  const float* x     = (const float*)d_in[0];
  const float* tc1_w = (const float*)d_in[1];  const float* tc1_b = (const float*)d_in[2];
  const float* tc1_s = (const float*)d_in[3];  const float* tc1_t = (const float*)d_in[4];
  const float* tc2_w = (const float*)d_in[5];  const float* tc2_b = (const float*)d_in[6];
  const float* tc2_s = (const float*)d_in[7];  const float* tc2_t = (const float*)d_in[8];
  const float* rx_w  = (const float*)d_in[9];  const float* rx_b  = (const float*)d_in[10];
  const float* rx_s  = (const float*)d_in[11]; const float* rx_t  = (const float*)d_in[12];
  const float* cc1_w = (const float*)d_in[13]; const float* cc1_b = (const float*)d_in[14];
  const float* cc1_s = (const float*)d_in[15]; const float* cc1_t = (const float*)d_in[16];
  const float* cc2_w = (const float*)d_in[17]; const float* cc2_b = (const float*)d_in[18];
  const float* cc2_s = (const float*)d_in[19]; const float* cc2_t = (const float*)d_in[20];
  const float* rd1_w = (const float*)d_in[21]; const float* rd1_b = (const float*)d_in[22];
  const float* rd1_s = (const float*)d_in[23]; const float* rd1_t = (const float*)d_in[24];
  const float* rd2_w = (const float*)d_in[25]; const float* rd2_b = (const float*)d_in[26];
  const float* rd2_s = (const float*)d_in[27]; const float* rd2_t = (const float*)d_in[28];
  const float* up1_w = (const float*)d_in[29]; const float* up1_b = (const float*)d_in[30];
  const float* up1_s = (const float*)d_in[31]; const float* up1_t = (const float*)d_in[32];
  const float* up2_w = (const float*)d_in[33]; const float* up2_b = (const float*)d_in[34];
  const float* up2_s = (const float*)d_in[35]; const float* up2_t = (const float*)d_in[36];
  const float* up3_w = (const float*)d_in[37]; const float* up3_b = (const float*)d_in[38];
  const float* wr    = (const float*)d_in[39];
  const float* wd    = (const float*)d_in[40];
  float* ws  = (float*)d_ws;
  float* out = (float*)d_out;

  k_repack<<<1024, 256, 0, stream>>>(rx_w, rx_s,
                                     cc1_w, cc1_b, cc1_s, cc1_t,
                                     cc2_w, cc2_b, cc2_s, cc2_t,
                                     rd1_w, rd1_b, rd1_s, rd1_t,
                                     rd2_w, rd2_b, rd2_s, rd2_t,
                                     up1_w, up1_b, up1_s, up1_t,
                                     up2_w, up2_b, up2_s, up2_t, ws);
  k_front<<<1024, 256, 0, stream>>>(x, tc1_w, tc1_b, tc1_s, tc1_t,
                                    tc2_w, tc2_b, tc2_s, tc2_t,
                                    ws + OFF_WRX, rx_b, rx_s, rx_t, ws + OFF_A);
  k_cc1<<<1024, 256, 0, stream>>>(ws + OFF_A, ws + OFF_WCC1, ws + OFF_P);
  k_mid<<<512, 256, 0, stream>>>(ws + OFF_P, ws + OFF_BCC1,
                                 ws + OFF_WCC2, ws + OFF_BCC2,
                                 ws + OFF_WRD1, ws + OFF_BRD1,
                                 ws + OFF_WRD2, ws + OFF_BRD2, ws + OFF_R);
  k_up1<<<512, 192, 0, stream>>>(ws + OFF_R, ws + OFF_WUP1, ws + OFF_BUP1, ws + OFF_U1);
  k_up2<<<512, 192, 0, stream>>>(ws + OFF_U1, ws + OFF_WUP2, ws + OFF_BUP2, up3_w, up3_b, ws + OFF_H);
  k_spec<<<64, 64, 0, stream>>>(ws + OFF_H, wr, wd, out);
}

// Round 5
// 392.687 us; speedup vs baseline: 1.0705x; 1.0705x over previous
//
#include <hip/hip_runtime.h>
#include <math.h>

// Workspace float offsets
#define OFF_A      0u          // A (16,2048,256) fp32          8388608
#define OFF_P      8388608u    // cc1 partials [8][16][256][64] 2097152
#define OFF_WCC1   10485760u   // [c2][oc][4]                    524288
#define OFF_BCC1   11010048u   // 64
#define OFF_WCC2   11010112u   // [ic][oc][4]                     16384
#define OFF_BCC2   11026496u   // 64
#define OFF_WRD1   11026560u   // [ic64][oc128][4]                32768
#define OFF_BRD1   11059328u   // 128
#define OFF_WRD2   11059456u   // [ic128][oc128][4]               65536
#define OFF_BRD2   11124992u   // 128
#define OFF_WUP1   11125120u   // [v3][ic128][oc64][4]            98304
#define OFF_BUP1   11223424u   // 64
#define OFF_WUP2   11223488u   // [v5][src3][ic64][oc32][4]      122880
#define OFF_BUP2   11346368u   // 32
#define OFF_WRX    11346400u   // folded rx weights [rxi][ic32][oc32] 4096
#define OFF_W1F    11350496u   // folded tc1 weights [oc16][6]        96
#define OFF_B1F    11350592u   // 16
#define OFF_W2F    11350608u   // folded tc2 weights [ic16][k3][oc32] 1536
#define OFF_B2F    11352144u   // 32
#define OFF_BRXF   11352176u   // 32
// Aliased over A (A dead after k_cc1):
#define OFF_R      0u          // R [16][256][128]               524288
#define OFF_U1     524288u     // U1 [16][3][256][64]            786432
#define OFF_H      1310720u    // H [16][5][256]                  20480
// total ws floats 11352208 (~43.3 MiB)

__device__ __forceinline__ void fma4(float4& a, const float4& x, float w) {
  a.x = fmaf(x.x, w, a.x); a.y = fmaf(x.y, w, a.y);
  a.z = fmaf(x.z, w, a.z); a.w = fmaf(x.w, w, a.w);
}

// ---------------------------------------------------------------- repack ----
__global__ __launch_bounds__(256) void k_repack(
    const float* __restrict__ tc1_w, const float* __restrict__ tc1_b, const float* __restrict__ tc1_s, const float* __restrict__ tc1_t,
    const float* __restrict__ tc2_w, const float* __restrict__ tc2_b, const float* __restrict__ tc2_s, const float* __restrict__ tc2_t,
    const float* __restrict__ rx_w, const float* __restrict__ rx_b, const float* __restrict__ rx_s, const float* __restrict__ rx_t,
    const float* __restrict__ cc1_w, const float* __restrict__ cc1_b, const float* __restrict__ cc1_s, const float* __restrict__ cc1_t,
    const float* __restrict__ cc2_w, const float* __restrict__ cc2_b, const float* __restrict__ cc2_s, const float* __restrict__ cc2_t,
    const float* __restrict__ rd1_w, const float* __restrict__ rd1_b, const float* __restrict__ rd1_s, const float* __restrict__ rd1_t,
    const float* __restrict__ rd2_w, const float* __restrict__ rd2_b, const float* __restrict__ rd2_s, const float* __restrict__ rd2_t,
    const float* __restrict__ up1_w, const float* __restrict__ up1_b, const float* __restrict__ up1_s, const float* __restrict__ up1_t,
    const float* __restrict__ up2_w, const float* __restrict__ up2_b, const float* __restrict__ up2_s, const float* __restrict__ up2_t,
    float* __restrict__ ws)
{
  const int tid = blockIdx.x * blockDim.x + threadIdx.x;
  const int nth = gridDim.x * blockDim.x;

  // front-end folded weights (all consumed as wave-uniform scalar loads)
  for (int i = tid; i < 96; i += nth) ws[OFF_W1F + i] = tc1_w[i] * tc1_s[i/6];
  for (int i = tid; i < 16; i += nth) ws[OFF_B1F + i] = tc1_b[i]*tc1_s[i] + tc1_t[i];
  for (int i = tid; i < 1536; i += nth) {
    int oc = i & 31, r = i >> 5, k = r % 3, ic = r / 3;
    ws[OFF_W2F + i] = tc2_w[oc*48 + ic*3 + k] * tc2_s[oc];
  }
  for (int i = tid; i < 32; i += nth) ws[OFF_B2F + i] = tc2_b[i]*tc2_s[i] + tc2_t[i];
  for (int i = tid; i < 4096; i += nth) {
    int oc = i & 31, ic = (i >> 5) & 31, rxi = i >> 10;
    ws[OFF_WRX + i] = rx_w[(oc*32 + ic)*4 + rxi] * rx_s[oc];
  }
  for (int i = tid; i < 32; i += nth) ws[OFF_BRXF + i] = rx_b[i]*rx_s[i] + rx_t[i];

  for (int i = tid; i < 2048*64*4; i += nth) {
    int k = i & 3, oc = (i >> 2) & 63, c2 = i >> 8;
    ws[OFF_WCC1 + i] = (k < 3) ? cc1_w[((oc*2048 + c2)*3 + 1)*3 + k] * cc1_s[oc] : 0.f;
  }
  for (int i = tid; i < 64; i += nth) ws[OFF_BCC1 + i] = cc1_b[i]*cc1_s[i] + cc1_t[i];

  for (int i = tid; i < 64*64*4; i += nth) {
    int k = i & 3, oc = (i >> 2) & 63, ic = i >> 8;
    ws[OFF_WCC2 + i] = (k < 3) ? cc2_w[((oc*64 + ic)*3 + 1)*3 + k] * cc2_s[oc] : 0.f;
  }
  for (int i = tid; i < 64; i += nth) ws[OFF_BCC2 + i] = cc2_b[i]*cc2_s[i] + cc2_t[i];

  for (int i = tid; i < 64*128*4; i += nth) {
    int k = i & 3, oc = (i >> 2) & 127, ic = i >> 9;
    ws[OFF_WRD1 + i] = (k < 3) ? rd1_w[((oc*64 + ic)*3 + 1)*3 + k] * rd1_s[oc] : 0.f;
  }
  for (int i = tid; i < 128; i += nth) ws[OFF_BRD1 + i] = rd1_b[i]*rd1_s[i] + rd1_t[i];

  for (int i = tid; i < 128*128*4; i += nth) {
    int k = i & 3, oc = (i >> 2) & 127, ic = i >> 9;
    ws[OFF_WRD2 + i] = (k < 3) ? rd2_w[((oc*128 + ic)*3 + 1)*3 + k] * rd2_s[oc] : 0.f;
  }
  for (int i = tid; i < 128; i += nth) ws[OFF_BRD2 + i] = rd2_b[i]*rd2_s[i] + rd2_t[i];

  for (int i = tid; i < 3*128*64*4; i += nth) {
    int k = i & 3, oc = (i >> 2) & 63, ic = (i >> 8) & 127, v = i >> 15;
    float val = 0.f;
    if (k < 3) {
      const int m = (v == 0) ? 6 : (v == 1) ? 7 : 3;
      float a = 0.f;
      for (int kh = 0; kh < 3; ++kh)
        if ((m >> kh) & 1) a += up1_w[((oc*128 + ic)*3 + kh)*3 + k];
      val = a * up1_s[oc];
    }
    ws[OFF_WUP1 + i] = val;
  }
  for (int i = tid; i < 64; i += nth) ws[OFF_BUP1 + i] = up1_b[i]*up1_s[i] + up1_t[i];

  for (int i = tid; i < 5*3*64*32*4; i += nth) {
    int k = i & 3, oc = (i >> 2) & 31, ic = (i >> 7) & 63, t = i >> 13;
    int src = t % 3, v = t / 3;
    float val = 0.f;
    if (k < 3) {
      const int MASKS[15] = {2,4,0,  1,6,0,  0,7,0,  0,3,4,  0,1,2};
      const int m = MASKS[v*3 + src];
      float a = 0.f;
      for (int kh = 0; kh < 3; ++kh)
        if ((m >> kh) & 1) a += up2_w[((oc*64 + ic)*3 + kh)*3 + k];
      val = a * up2_s[oc];
    }
    ws[OFF_WUP2 + i] = val;
  }
  for (int i = tid; i < 32; i += nth) ws[OFF_BUP2 + i] = up2_b[i]*up2_s[i] + up2_t[i];
}

// ------------------------------------------------- fused tc1+tc2+rx ---------
// Thread = one sample; t2[32] and acc[32] in registers. LDS holds ONLY t1
// (stride-1 b32, conflict-free, halo-padded). All weights are wave-uniform
// global reads -> scalar loads feeding v_fmac SGPR operands.
__global__ __launch_bounds__(256, 4) void k_front(
    const float* __restrict__ x, const float* __restrict__ ws, float* __restrict__ A)
{
  __shared__ float t1s[16][258];   // column s+1; cols 0 and 257 are zero halo
  const int tid = threadIdx.x;
  const int b = blockIdx.x >> 6, chirp = blockIdx.x & 63;
  const int s = tid;

  if (tid < 32) { int o = tid & 15; int c = (tid >> 4) ? 257 : 0; t1s[o][c] = 0.f; }

  const float* w1f  = ws + OFF_W1F;
  const float* b1f  = ws + OFF_B1F;
  const float* w2f  = ws + OFF_W2F;
  const float* b2f  = ws + OFF_B2F;
  const float* wrxf = ws + OFF_WRX;
  const float* brxf = ws + OFF_BRXF;

  float acc[32];
  #pragma unroll
  for (int j = 0; j < 32; ++j) acc[j] = 0.f;

  #pragma unroll 1
  for (int rxi = 0; rxi < 4; ++rxi) {
    // ---- phase A: t1 for my sample -> LDS ----
    {
      const float2* xb2 = (const float2*)(x + ((size_t)(((b*4 + rxi)*64 + chirp)*256) << 1));
      float2 xm = xb2[s];
      float2 xl = xb2[(s == 0) ? 0 : (s - 1)];
      float2 xr = xb2[(s == 255) ? 255 : (s + 1)];
      if (s == 0)   { xl.x = 0.f; xl.y = 0.f; }
      if (s == 255) { xr.x = 0.f; xr.y = 0.f; }
      #pragma unroll 4
      for (int o = 0; o < 16; ++o) {
        const float* w = w1f + o*6;
        float v = b1f[o];
        v = fmaf(xl.x, w[0], v);
        v = fmaf(xm.x, w[1], v);
        v = fmaf(xr.x, w[2], v);
        v = fmaf(xl.y, w[3], v);
        v = fmaf(xm.y, w[4], v);
        v = fmaf(xr.y, w[5], v);
        t1s[o][s+1] = fmaxf(v, 0.f);
      }
    }
    __syncthreads();

    // ---- phase B: t2[32] in registers; t1 windows from LDS (stride-1) ----
    float t2[32];
    #pragma unroll
    for (int j = 0; j < 32; ++j) t2[j] = b2f[j];
    #pragma unroll 2
    for (int ic = 0; ic < 16; ++ic) {
      float tl = t1s[ic][s];
      float tm = t1s[ic][s+1];
      float tr = t1s[ic][s+2];
      const float* w = w2f + ic*96;
      #pragma unroll
      for (int oc = 0; oc < 32; ++oc)
        t2[oc] = fmaf(tl, w[oc], fmaf(tm, w[32+oc], fmaf(tr, w[64+oc], t2[oc])));
    }
    #pragma unroll
    for (int j = 0; j < 32; ++j) t2[j] = fmaxf(t2[j], 0.f);

    // ---- phase C: rx 1x1, no LDS ----
    const float* wr0 = wrxf + rxi*1024;
    #pragma unroll 4
    for (int ic = 0; ic < 32; ++ic) {
      float tv = t2[ic];
      const float* w = wr0 + ic*32;
      #pragma unroll
      for (int oc = 0; oc < 32; ++oc)
        acc[oc] = fmaf(tv, w[oc], acc[oc]);
    }
    __syncthreads();   // protect t1s before next rxi's phase A write
  }

  #pragma unroll 4
  for (int oc = 0; oc < 32; ++oc) {
    float v = fmaxf(acc[oc] + brxf[oc], 0.f);
    A[(size_t)((b*2048 + oc*64 + chirp)*256) + s] = v;
  }
}

// --------------------------------------------------------- cc1 (split-K8) ---
__global__ __launch_bounds__(256) void k_cc1(
    const float* __restrict__ A, const float* __restrict__ wp, float* __restrict__ P)
{
  __shared__ __align__(16) float As[256][36];   // samples s0-1 .. s0+32 at si 0..33
  const int tid = threadIdx.x;
  const int ks = blockIdx.x & 7;
  const int stile = (blockIdx.x >> 3) & 7;
  const int b = blockIdx.x >> 6;
  const int s0 = stile * 32;
  const int oc = tid & 63;
  const int sg = tid >> 6;
  const int cbase = ks * 256;
  const float4* w4 = (const float4*)wp;

  for (int i = tid; i < 256*36; i += 256) {
    int c = i / 36, si = i - c*36;
    int sA = s0 - 1 + si;
    float v = 0.f;
    if (si < 34 && sA >= 0 && sA < 256)
      v = A[(size_t)(b*2048 + cbase + c)*256 + sA];
    As[c][si] = v;
  }
  __syncthreads();

  const int sb = sg * 8;
  float4 acc0 = make_float4(0.f,0.f,0.f,0.f);
  float4 acc1 = make_float4(0.f,0.f,0.f,0.f);
  #pragma unroll 4
  for (int c = 0; c < 256; ++c) {
    float4 w = w4[(size_t)(cbase + c)*64 + oc];
    float4 a0 = *(const float4*)&As[c][sb];
    float4 a1 = *(const float4*)&As[c][sb + 4];
    float2 a2 = *(const float2*)&As[c][sb + 8];
    acc0.x = fmaf(a0.x,w.x, fmaf(a0.y,w.y, fmaf(a0.z,w.z, acc0.x)));
    acc0.y = fmaf(a0.y,w.x, fmaf(a0.z,w.y, fmaf(a0.w,w.z, acc0.y)));
    acc0.z = fmaf(a0.z,w.x, fmaf(a0.w,w.y, fmaf(a1.x,w.z, acc0.z)));
    acc0.w = fmaf(a0.w,w.x, fmaf(a1.x,w.y, fmaf(a1.y,w.z, acc0.w)));
    acc1.x = fmaf(a1.x,w.x, fmaf(a1.y,w.y, fmaf(a1.z,w.z, acc1.x)));
    acc1.y = fmaf(a1.y,w.x, fmaf(a1.z,w.y, fmaf(a1.w,w.z, acc1.y)));
    acc1.z = fmaf(a1.z,w.x, fmaf(a1.w,w.y, fmaf(a2.x,w.z, acc1.z)));
    acc1.w = fmaf(a1.w,w.x, fmaf(a2.x,w.y, fmaf(a2.y,w.z, acc1.w)));
  }
  float* Pk = P + ((size_t)(ks*16 + b)*256)*64;
  int s = s0 + sb;
  Pk[(size_t)(s+0)*64 + oc] = acc0.x;
  Pk[(size_t)(s+1)*64 + oc] = acc0.y;
  Pk[(size_t)(s+2)*64 + oc] = acc0.z;
  Pk[(size_t)(s+3)*64 + oc] = acc0.w;
  Pk[(size_t)(s+4)*64 + oc] = acc1.x;
  Pk[(size_t)(s+5)*64 + oc] = acc1.y;
  Pk[(size_t)(s+6)*64 + oc] = acc1.z;
  Pk[(size_t)(s+7)*64 + oc] = acc1.w;
}

// ------------------------------------------- fused cc2 + rd1 + rd2 ----------
__global__ __launch_bounds__(256) void k_mid(
    const float* __restrict__ P, const float* __restrict__ bcc1,
    const float* __restrict__ wcc2, const float* __restrict__ bcc2,
    const float* __restrict__ wrd1, const float* __restrict__ brd1,
    const float* __restrict__ wrd2, const float* __restrict__ brd2,
    float* __restrict__ R)
{
  __shared__ float c1s[14][64];   // c1 at s0-3 .. s0+10
  __shared__ float c2s[14][64];   // c2 at s0-2 .. s0+9 (rows 12,13 zero pad)
  __shared__ float r1s[10][128];  // r1 at s0-1 .. s0+8
  const int tid = threadIdx.x;
  const int b = blockIdx.x >> 5;
  const int s0 = (blockIdx.x & 31) * 8;
  const float4* wc2 = (const float4*)wcc2;
  const float4* wr1 = (const float4*)wrd1;
  const float4* wr2 = (const float4*)wrd2;

  for (int i = tid; i < 14*64; i += 256) {
    int si = i >> 6, ic = i & 63;
    int sA = s0 - 3 + si;
    float v = 0.f;
    if (sA >= 0 && sA < 256) {
      float a = bcc1[ic];
      #pragma unroll
      for (int ksp = 0; ksp < 8; ++ksp)
        a += P[((size_t)(ksp*16 + b)*256 + sA)*64 + ic];
      v = fmaxf(a, 0.f);
    }
    c1s[si][ic] = v;
  }
  __syncthreads();

  {
    const int g = tid >> 6, oc = tid & 63;
    if (g < 3) {
      float4 acc;
      float bb = bcc2[oc];
      acc = make_float4(bb, bb, bb, bb);
      for (int ic = 0; ic < 64; ++ic) {
        float4 w = wc2[ic*64 + oc];
        float c0 = c1s[g*4+0][ic], c1 = c1s[g*4+1][ic], c2 = c1s[g*4+2][ic];
        float c3 = c1s[g*4+3][ic], c4 = c1s[g*4+4][ic], c5 = c1s[g*4+5][ic];
        acc.x = fmaf(c0,w.x, fmaf(c1,w.y, fmaf(c2,w.z, acc.x)));
        acc.y = fmaf(c1,w.x, fmaf(c2,w.y, fmaf(c3,w.z, acc.y)));
        acc.z = fmaf(c2,w.x, fmaf(c3,w.y, fmaf(c4,w.z, acc.z)));
        acc.w = fmaf(c3,w.x, fmaf(c4,w.y, fmaf(c5,w.z, acc.w)));
      }
      c2s[g*4+0][oc] = fmaxf(acc.x, 0.f);
      c2s[g*4+1][oc] = fmaxf(acc.y, 0.f);
      c2s[g*4+2][oc] = fmaxf(acc.z, 0.f);
      c2s[g*4+3][oc] = fmaxf(acc.w, 0.f);
    } else {
      int k = tid - 192;
      c2s[12][k] = 0.f;
      c2s[13][k] = 0.f;
    }
  }
  __syncthreads();

  for (int it = tid; it < 384; it += 256) {
    const int oc = it & 127, g = it >> 7;
    float4 acc;
    float bb = brd1[oc];
    acc = make_float4(bb, bb, bb, bb);
    for (int ic = 0; ic < 64; ++ic) {
      float4 w = wr1[ic*128 + oc];
      float c0 = c2s[g*4+0][ic], c1 = c2s[g*4+1][ic], c2 = c2s[g*4+2][ic];
      float c3 = c2s[g*4+3][ic], c4 = c2s[g*4+4][ic], c5 = c2s[g*4+5][ic];
      acc.x = fmaf(c0,w.x, fmaf(c1,w.y, fmaf(c2,w.z, acc.x)));
      acc.y = fmaf(c1,w.x, fmaf(c2,w.y, fmaf(c3,w.z, acc.y)));
      acc.z = fmaf(c2,w.x, fmaf(c3,w.y, fmaf(c4,w.z, acc.z)));
      acc.w = fmaf(c3,w.x, fmaf(c4,w.y, fmaf(c5,w.z, acc.w)));
    }
    r1s[g*4+0][oc] = fmaxf(acc.x, 0.f);
    r1s[g*4+1][oc] = fmaxf(acc.y, 0.f);
    if (g < 2) {
      r1s[g*4+2][oc] = fmaxf(acc.z, 0.f);
      r1s[g*4+3][oc] = fmaxf(acc.w, 0.f);
    }
  }
  __syncthreads();

  {
    const int g = tid >> 7, oc = tid & 127;
    float4 acc;
    float bb = brd2[oc];
    acc = make_float4(bb, bb, bb, bb);
    for (int ic = 0; ic < 128; ++ic) {
      float4 w = wr2[ic*128 + oc];
      float c0 = r1s[g*4+0][ic], c1 = r1s[g*4+1][ic], c2 = r1s[g*4+2][ic];
      float c3 = r1s[g*4+3][ic], c4 = r1s[g*4+4][ic], c5 = r1s[g*4+5][ic];
      acc.x = fmaf(c0,w.x, fmaf(c1,w.y, fmaf(c2,w.z, acc.x)));
      acc.y = fmaf(c1,w.x, fmaf(c2,w.y, fmaf(c3,w.z, acc.y)));
      acc.z = fmaf(c2,w.x, fmaf(c3,w.y, fmaf(c4,w.z, acc.z)));
      acc.w = fmaf(c3,w.x, fmaf(c4,w.y, fmaf(c5,w.z, acc.w)));
    }
    int s = s0 + g*4;
    R[((size_t)b*256 + s+0)*128 + oc] = fmaxf(acc.x, 0.f);
    R[((size_t)b*256 + s+1)*128 + oc] = fmaxf(acc.y, 0.f);
    R[((size_t)b*256 + s+2)*128 + oc] = fmaxf(acc.z, 0.f);
    R[((size_t)b*256 + s+3)*128 + oc] = fmaxf(acc.w, 0.f);
  }
}

// --------------------------------------- up1 on 3 distinct rows -------------
__global__ __launch_bounds__(192) void k_up1(
    const float* __restrict__ R, const float* __restrict__ wup1, const float* __restrict__ bup1,
    float* __restrict__ U1)
{
  __shared__ float Rs[10][128];   // s0-1 .. s0+8
  const int tid = threadIdx.x;
  const int b = blockIdx.x >> 5;
  const int s0 = (blockIdx.x & 31) * 8;
  for (int i = tid; i < 10*128; i += 192) {
    int si = i >> 7, ic = i & 127;
    int sA = s0 - 1 + si;
    Rs[si][ic] = (sA >= 0 && sA < 256) ? R[((size_t)b*256 + sA)*128 + ic] : 0.f;
  }
  __syncthreads();
  const int vi = tid >> 6, oc = tid & 63;
  const float4* w4 = (const float4*)wup1;
  float acc[8];
  float bb = bup1[oc];
  #pragma unroll
  for (int j = 0; j < 8; ++j) acc[j] = bb;
  for (int ic = 0; ic < 128; ++ic) {
    float4 w = w4[(vi*128 + ic)*64 + oc];
    float r0 = Rs[0][ic], r1 = Rs[1][ic], r2 = Rs[2][ic], r3 = Rs[3][ic], r4 = Rs[4][ic];
    float r5 = Rs[5][ic], r6 = Rs[6][ic], r7 = Rs[7][ic], r8 = Rs[8][ic], r9 = Rs[9][ic];
    acc[0] = fmaf(r0,w.x, fmaf(r1,w.y, fmaf(r2,w.z, acc[0])));
    acc[1] = fmaf(r1,w.x, fmaf(r2,w.y, fmaf(r3,w.z, acc[1])));
    acc[2] = fmaf(r2,w.x, fmaf(r3,w.y, fmaf(r4,w.z, acc[2])));
    acc[3] = fmaf(r3,w.x, fmaf(r4,w.y, fmaf(r5,w.z, acc[3])));
    acc[4] = fmaf(r4,w.x, fmaf(r5,w.y, fmaf(r6,w.z, acc[4])));
    acc[5] = fmaf(r5,w.x, fmaf(r6,w.y, fmaf(r7,w.z, acc[5])));
    acc[6] = fmaf(r6,w.x, fmaf(r7,w.y, fmaf(r8,w.z, acc[6])));
    acc[7] = fmaf(r7,w.x, fmaf(r8,w.y, fmaf(r9,w.z, acc[7])));
  }
  #pragma unroll
  for (int j = 0; j < 8; ++j)
    U1[((size_t)(b*3 + vi)*256 + s0 + j)*64 + oc] = fmaxf(acc[j], 0.f);
}

// ------------------------------- up2 (5 rows) + up3 + sigmoid ---------------
__global__ __launch_bounds__(192) void k_up2(
    const float* __restrict__ U1, const float* __restrict__ wup2, const float* __restrict__ bup2,
    const float* __restrict__ up3_w, const float* __restrict__ up3_b,
    float* __restrict__ H)
{
  __shared__ float u1s[3][10][64];
  __shared__ float u2s[5][32][9];
  const int tid = threadIdx.x;
  const int b = blockIdx.x >> 5;
  const int s0 = (blockIdx.x & 31) * 8;
  for (int i = tid; i < 3*10*64; i += 192) {
    int v = i / 640, r = i - v*640, si = r >> 6, ic = r & 63;
    int sA = s0 - 1 + si;
    u1s[v][si][ic] = (sA >= 0 && sA < 256) ? U1[((size_t)(b*3 + v)*256 + sA)*64 + ic] : 0.f;
  }
  __syncthreads();
  if (tid < 160) {
    const int v = tid >> 5, oc = tid & 31;
    const float4* w4 = (const float4*)wup2;
    float acc[8];
    float bb = bup2[oc];
    #pragma unroll
    for (int j = 0; j < 8; ++j) acc[j] = bb;
    for (int src = 0; src < 3; ++src)
      for (int ic = 0; ic < 64; ++ic) {
        float4 w = w4[((v*3 + src)*64 + ic)*32 + oc];
        float r0 = u1s[src][0][ic], r1 = u1s[src][1][ic], r2 = u1s[src][2][ic];
        float r3 = u1s[src][3][ic], r4 = u1s[src][4][ic], r5 = u1s[src][5][ic];
        float r6 = u1s[src][6][ic], r7 = u1s[src][7][ic], r8 = u1s[src][8][ic];
        float r9 = u1s[src][9][ic];
        acc[0] = fmaf(r0,w.x, fmaf(r1,w.y, fmaf(r2,w.z, acc[0])));
        acc[1] = fmaf(r1,w.x, fmaf(r2,w.y, fmaf(r3,w.z, acc[1])));
        acc[2] = fmaf(r2,w.x, fmaf(r3,w.y, fmaf(r4,w.z, acc[2])));
        acc[3] = fmaf(r3,w.x, fmaf(r4,w.y, fmaf(r5,w.z, acc[3])));
        acc[4] = fmaf(r4,w.x, fmaf(r5,w.y, fmaf(r6,w.z, acc[4])));
        acc[5] = fmaf(r5,w.x, fmaf(r6,w.y, fmaf(r7,w.z, acc[5])));
        acc[6] = fmaf(r6,w.x, fmaf(r7,w.y, fmaf(r8,w.z, acc[6])));
        acc[7] = fmaf(r7,w.x, fmaf(r8,w.y, fmaf(r9,w.z, acc[7])));
      }
    #pragma unroll
    for (int j = 0; j < 8; ++j) u2s[v][oc][j] = fmaxf(acc[j], 0.f);
  }
  __syncthreads();
  if (tid < 40) {
    int v = tid >> 3, j = tid & 7;
    float a = up3_b[0];
    for (int ic = 0; ic < 32; ++ic)
      a = fmaf(u2s[v][ic][j], up3_w[ic], a);
    H[(size_t)(b*5 + v)*256 + s0 + j] = 1.f / (1.f + expf(-a));
  }
}

// --------------------- range/Doppler spectral + magnitude + final -----------
__global__ __launch_bounds__(64) void k_spec(
    const float* __restrict__ H, const float* __restrict__ wr, const float* __restrict__ wd,
    float* __restrict__ out)
{
  __shared__ float hs[5][256];
  __shared__ float S0[64], S1[64];
  __shared__ float wds[4][64][2];
  const int tid = threadIdx.x;
  const int b = blockIdx.x >> 2;
  const int rt = blockIdx.x & 3;
  for (int i = tid; i < 1280; i += 64) hs[i >> 8][i & 255] = H[(size_t)b*1280 + i];
  {
    float a0 = 0.f, a1 = 0.f;
    for (int c = 2; c <= 61; ++c) {
      a0 += wd[(c*64 + tid)*2 + 0];
      a1 += wd[(c*64 + tid)*2 + 1];
    }
    S0[tid] = a0; S1[tid] = a1;
  }
  for (int i = tid; i < 512; i += 64) {
    int row = i >> 7, rem = i & 127, d = rem >> 1, comp = rem & 1;
    int c = (row < 2) ? row : (60 + row);   // rows 0,1,62,63
    wds[row][d][comp] = wd[(c*64 + d)*2 + comp];
  }
  __syncthreads();
  const int r = rt*64 + tid;
  float rr0=0,rr1=0,rr2=0,rr3=0,rr4=0, ri0=0,ri1=0,ri2=0,ri3=0,ri4=0;
  const float2* wr2p = (const float2*)wr;
  for (int s = 0; s < 256; ++s) {
    float2 w = wr2p[s*256 + r];
    float h0 = hs[0][s], h1 = hs[1][s], h2 = hs[2][s], h3 = hs[3][s], h4 = hs[4][s];
    rr0 = fmaf(h0, w.x, rr0); ri0 = fmaf(h0, w.y, ri0);
    rr1 = fmaf(h1, w.x, rr1); ri1 = fmaf(h1, w.y, ri1);
    rr2 = fmaf(h2, w.x, rr2); ri2 = fmaf(h2, w.y, ri2);
    rr3 = fmaf(h3, w.x, rr3); ri3 = fmaf(h3, w.y, ri3);
    rr4 = fmaf(h4, w.x, rr4); ri4 = fmaf(h4, w.y, ri4);
  }
  for (int d = 0; d < 64; ++d) {
    float w0r = wds[0][d][0], w0i = wds[0][d][1];
    float w1r = wds[1][d][0], w1i = wds[1][d][1];
    float w2r = wds[2][d][0], w2i = wds[2][d][1];
    float w3r = wds[3][d][0], w3i = wds[3][d][1];
    float s0v = S0[d], s1v = S1[d];
    float rdr = rr0*w0r + rr1*w1r + rr2*s0v + rr3*w2r + rr4*w3r
              - ri0*w0i - ri1*w1i - ri2*s1v - ri3*w2i - ri4*w3i;
    float rdi = rr0*w0i + rr1*w1i + rr2*s1v + rr3*w2i + rr4*w3i
              + ri0*w0r + ri1*w1r + ri2*s0v + ri3*w2r + ri4*w3r;
    float mag = sqrtf(rdr*rdr + rdi*rdi) * (1.0f / 16384.0f);
    int v = (d == 0) ? 0 : (d == 1) ? 1 : (d <= 61) ? 2 : ((d == 62) ? 3 : 4);
    float o = hs[v][r] + 0.1f * mag;
    out[(size_t)b*16384 + d*256 + r] = fminf(fmaxf(o, 0.f), 1.f);
  }
}

extern "C" void kernel_launch(void* const* d_in, const int* in_sizes, int n_in,
                              void* d_out, int out_size, void* d_ws, size_t ws_size,
                              hipStream_t stream)
{
  const float* x     = (const float*)d_in[0];
  const float* tc1_w = (const float*)d_in[1];  const float* tc1_b = (const float*)d_in[2];
  const float* tc1_s = (const float*)d_in[3];  const float* tc1_t = (const float*)d_in[4];
  const float* tc2_w = (const float*)d_in[5];  const float* tc2_b = (const float*)d_in[6];
  const float* tc2_s = (const float*)d_in[7];  const float* tc2_t = (const float*)d_in[8];
  const float* rx_w  = (const float*)d_in[9];  const float* rx_b  = (const float*)d_in[10];
  const float* rx_s  = (const float*)d_in[11]; const float* rx_t  = (const float*)d_in[12];
  const float* cc1_w = (const float*)d_in[13]; const float* cc1_b = (const float*)d_in[14];
  const float* cc1_s = (const float*)d_in[15]; const float* cc1_t = (const float*)d_in[16];
  const float* cc2_w = (const float*)d_in[17]; const float* cc2_b = (const float*)d_in[18];
  const float* cc2_s = (const float*)d_in[19]; const float* cc2_t = (const float*)d_in[20];
  const float* rd1_w = (const float*)d_in[21]; const float* rd1_b = (const float*)d_in[22];
  const float* rd1_s = (const float*)d_in[23]; const float* rd1_t = (const float*)d_in[24];
  const float* rd2_w = (const float*)d_in[25]; const float* rd2_b = (const float*)d_in[26];
  const float* rd2_s = (const float*)d_in[27]; const float* rd2_t = (const float*)d_in[28];
  const float* up1_w = (const float*)d_in[29]; const float* up1_b = (const float*)d_in[30];
  const float* up1_s = (const float*)d_in[31]; const float* up1_t = (const float*)d_in[32];
  const float* up2_w = (const float*)d_in[33]; const float* up2_b = (const float*)d_in[34];
  const float* up2_s = (const float*)d_in[35]; const float* up2_t = (const float*)d_in[36];
  const float* up3_w = (const float*)d_in[37]; const float* up3_b = (const float*)d_in[38];
  const float* wr    = (const float*)d_in[39];
  const float* wd    = (const float*)d_in[40];
  float* ws  = (float*)d_ws;
  float* out = (float*)d_out;

  k_repack<<<1024, 256, 0, stream>>>(tc1_w, tc1_b, tc1_s, tc1_t,
                                     tc2_w, tc2_b, tc2_s, tc2_t,
                                     rx_w, rx_b, rx_s, rx_t,
                                     cc1_w, cc1_b, cc1_s, cc1_t,
                                     cc2_w, cc2_b, cc2_s, cc2_t,
                                     rd1_w, rd1_b, rd1_s, rd1_t,
                                     rd2_w, rd2_b, rd2_s, rd2_t,
                                     up1_w, up1_b, up1_s, up1_t,
                                     up2_w, up2_b, up2_s, up2_t, ws);
  k_front<<<1024, 256, 0, stream>>>(x, ws, ws + OFF_A);
  k_cc1<<<1024, 256, 0, stream>>>(ws + OFF_A, ws + OFF_WCC1, ws + OFF_P);
  k_mid<<<512, 256, 0, stream>>>(ws + OFF_P, ws + OFF_BCC1,
                                 ws + OFF_WCC2, ws + OFF_BCC2,
                                 ws + OFF_WRD1, ws + OFF_BRD1,
                                 ws + OFF_WRD2, ws + OFF_BRD2, ws + OFF_R);
  k_up1<<<512, 192, 0, stream>>>(ws + OFF_R, ws + OFF_WUP1, ws + OFF_BUP1, ws + OFF_U1);
  k_up2<<<512, 192, 0, stream>>>(ws + OFF_U1, ws + OFF_WUP2, ws + OFF_BUP2, up3_w, up3_b, ws + OFF_H);
  k_spec<<<64, 64, 0, stream>>>(ws + OFF_H, wr, wd, out);
}